// Round 17
// baseline (237.568 us; speedup 1.0000x reference)
//
#include <hip/hip_runtime.h>
#include <hip/hip_cooperative_groups.h>

namespace cg = cooperative_groups;

// RNN-T loss forward: B=8, T=128, U=100, V=1024, BLANK=0.
// out = mean_b of -( alpha[tl-2, ul] + blank_lp[tl-2, ul] )
//
// Single cooperative kernel:
//  phase 1: grid-stride log-softmax over all (b,t,u) rows; stage the two
//    needed PROBABILITIES (bf16) into diagonal-major interleaved staging
//    gS[b][d][u>>1][B0,B1,E0,E1].
//  grid.sync() (one grid-wide release; cross-XCD visibility)
//  phase 2: 8 consumer waves (blocks 0..7, wave 0) run 232 diagonals of
//    f32 FMA  n1=fma(P1,B1,P0*E1); n0=fma(P0,B0,shr1(P1)*E0)  reading
//    staging directly from global (L3-resident) with a 3-deep register
//    group buffer; wave-max rescale every 8 diagonals; fused mean via
//    8 device-scope atomics.
// Fallback (if cooperative launch unavailable): same code as two kernels.

constexpr int Bb = 8;
constexpr int Tt = 128;
constexpr int Uu = 100;
constexpr int Vv = 1024;
constexpr int UP1 = Uu + 1;
constexpr int NROWS = Bb * Tt * UP1;  // 103424
constexpr int DROWS = 244;            // staging rows per batch
constexpr int PAIRS = 52;             // u-pairs per row
constexpr int ROWB  = PAIRS * 8;      // 416 bytes per row

// ---- bf16 helpers --------------------------------------------------------
__device__ __forceinline__ unsigned short f2bf(float f) {
    unsigned int u = __builtin_bit_cast(unsigned int, f);
    u += 0x7fffu + ((u >> 16) & 1u);
    return (unsigned short)(u >> 16);
}
__device__ __forceinline__ float bflo(unsigned int p) {
    return __builtin_bit_cast(float, p << 16);
}
__device__ __forceinline__ float bfhi(unsigned int p) {
    return __builtin_bit_cast(float, p & 0xffff0000u);
}

// lane l receives lane l-1's value; lane 0 -> 0 (prob identity)
__device__ __forceinline__ float wave_shr1(float x) {
    return __builtin_bit_cast(float, __builtin_amdgcn_update_dpp(
        0, __builtin_bit_cast(int, x), 0x138, 0xf, 0xf, true));
}
__device__ __forceinline__ float readlane_f(float x, int lane) {
    return __builtin_bit_cast(float,
        __builtin_amdgcn_readlane(__builtin_bit_cast(int, x), lane));
}

#define DPP_MAXSTEP(x, ctrl, rmask) {                                        \
    float _t = __builtin_bit_cast(float, __builtin_amdgcn_update_dpp(        \
        __builtin_bit_cast(int, x), __builtin_bit_cast(int, x),              \
        ctrl, rmask, 0xf, false));                                           \
    x = fmaxf(x, _t); }
#define WAVE_SCAN_MAX(x)           \
    DPP_MAXSTEP(x, 0x111, 0xf);    \
    DPP_MAXSTEP(x, 0x112, 0xf);    \
    DPP_MAXSTEP(x, 0x114, 0xf);    \
    DPP_MAXSTEP(x, 0x118, 0xf);    \
    DPP_MAXSTEP(x, 0x142, 0xa);    \
    DPP_MAXSTEP(x, 0x143, 0xc)

// ---- shared lse row body -------------------------------------------------
__device__ __forceinline__ void lse_row(
        int wid, int lane,
        const float* __restrict__ logits,
        const int*   __restrict__ targets,
        unsigned short* __restrict__ gS) {
    const int b   = wid / (Tt * UP1);
    const int rem = wid - b * (Tt * UP1);
    const int t   = rem / UP1;
    const int u   = rem - t * UP1;

    const float* row = logits + (size_t)wid * Vv;
    const float4* r4 = (const float4*)row;
    float4 x0 = r4[lane];
    float4 x1 = r4[lane + 64];
    float4 x2 = r4[lane + 128];
    float4 x3 = r4[lane + 192];

    float m = fmaxf(fmaxf(fmaxf(x0.x, x0.y), fmaxf(x0.z, x0.w)),
                    fmaxf(fmaxf(x1.x, x1.y), fmaxf(x1.z, x1.w)));
    m = fmaxf(m, fmaxf(fmaxf(fmaxf(x2.x, x2.y), fmaxf(x2.z, x2.w)),
                       fmaxf(fmaxf(x3.x, x3.y), fmaxf(x3.z, x3.w))));
    #pragma unroll
    for (int d = 32; d > 0; d >>= 1) m = fmaxf(m, __shfl_xor(m, d, 64));

    float s = __expf(x0.x - m) + __expf(x0.y - m) + __expf(x0.z - m) + __expf(x0.w - m)
            + __expf(x1.x - m) + __expf(x1.y - m) + __expf(x1.z - m) + __expf(x1.w - m)
            + __expf(x2.x - m) + __expf(x2.y - m) + __expf(x2.z - m) + __expf(x2.w - m)
            + __expf(x3.x - m) + __expf(x3.y - m) + __expf(x3.z - m) + __expf(x3.w - m);
    #pragma unroll
    for (int d = 32; d > 0; d >>= 1) s += __shfl_xor(s, d, 64);

    float lse = m + __logf(s);

    if (lane == 0) {
        const int dw = t + u + 1;                       // 1..228
        const size_t rowoff = ((size_t)b * DROWS + dw) * (PAIRS * 4);
        gS[rowoff + (u >> 1) * 4 + (u & 1)] = f2bf(__expf(x0.x - lse));
        if (u < Uu) {
            int tgt = targets[b * Uu + u];
            const int sidx = u + 1;
            gS[rowoff + (sidx >> 1) * 4 + 2 + (sidx & 1)] = f2bf(__expf(row[tgt] - lse));
        }
    }
}

// ---- shared dp consumer (one wave per batch; staging read from global) ---
__device__ __forceinline__ void dp_consume(
        int b, int lane,
        const unsigned short* __restrict__ gS,
        const int* __restrict__ logit_lengths,
        const int* __restrict__ target_lengths,
        float* __restrict__ nll,
        int*   __restrict__ dcnt,
        float* __restrict__ out) {
    const int tl = logit_lengths[b];
    const int ul = target_lengths[b];
    const int t_idx = tl - 2;           // reference reads alpha[tl-2][ul]
    const int dcap  = t_idx + ul;       // diagonal of the readout cell

    const int lpair = (lane < 51) ? lane : 51;   // lanes>=51: garbage lanes
    const char* gbase = (const char*)gS + (size_t)b * DROWS * ROWB + lpair * 8;

    float P0 = (lane == 0) ? 1.0f : 0.0f;   // exp(alpha) on diag 0
    float P1 = 0.0f;
    float S  = 0.0f;
    float capP0 = (dcap == 0) ? 1.0f : 0.0f, capP1 = 0.0f, capS = 0.0f;

#define PSTEP(dv, w0, w1) do {                                         \
        float Bx = bflo(w0), By = bfhi(w0);                            \
        float Ex = bflo(w1), Ey = bfhi(w1);                            \
        float sh = wave_shr1(P1);                                      \
        float n1 = fmaf(P1, By, P0 * Ey);                              \
        float n0 = fmaf(P0, Bx, sh * Ex);                              \
        P0 = n0; P1 = n1;                                              \
        if ((dv) == dcap) { capP0 = n0; capP1 = n1; capS = S; }        \
    } while (0)

#define RESCALE do {                                                   \
        float gm = fmaxf(P0, P1);                                      \
        WAVE_SCAN_MAX(gm);                                             \
        float mm = fmaxf(readlane_f(gm, 63), 1e-30f);                  \
        float rr = 1.0f / mm;                                          \
        P0 *= rr; P1 *= rr;                                            \
        S += __logf(mm);                                               \
    } while (0)

    // group k covers diagonals 8k+1 .. 8k+8 (k = 0..28)
#define GLOADG(UB, UE, k) do {                                         \
        _Pragma("unroll")                                              \
        for (int r = 0; r < 8; ++r) {                                  \
            uint2 q = *(const uint2*)(gbase +                          \
                        (size_t)((k) * 8 + 1 + r) * ROWB);             \
            UB[r] = q.x; UE[r] = q.y;                                  \
        }                                                              \
    } while (0)

#define COMPG(UB, UE, k) do {                                          \
        _Pragma("unroll")                                              \
        for (int r = 0; r < 8; ++r)                                    \
            PSTEP((k) * 8 + 1 + r, UB[r], UE[r]);                      \
        RESCALE;                                                       \
    } while (0)

    unsigned int Ab[8], Ae[8], Bf[8], Be[8], Cb[8], Ce[8];
    GLOADG(Ab, Ae, 0);
    GLOADG(Bf, Be, 1);
    GLOADG(Cb, Ce, 2);
    for (int c = 0; c < 9; ++c) {       // groups 0..26, loads up to 28
        const int k = 3 * c;
        COMPG(Ab, Ae, k);     if (k + 3 < 29) GLOADG(Ab, Ae, k + 3);
        COMPG(Bf, Be, k + 1); if (k + 4 < 29) GLOADG(Bf, Be, k + 4);
        COMPG(Cb, Ce, k + 2); if (k + 5 < 29) GLOADG(Cb, Ce, k + 5);
    }
    COMPG(Ab, Ae, 27);
    COMPG(Bf, Be, 28);                  // -> diagonal 232
#undef PSTEP
#undef RESCALE
#undef GLOADG
#undef COMPG

    // readout: cap value lives on lane ul>>1, slot ul&1
    float w0 = readlane_f(capP0, ul >> 1);
    float w1 = readlane_f(capP1, ul >> 1);
    float capv = (ul & 1) ? w1 : w0;

    if (lane == 0) {
        const unsigned short* gb =
            gS + (size_t)b * DROWS * PAIRS * 4;
        unsigned short hv = gb[(size_t)(dcap + 1) * PAIRS * 4
                               + (ul >> 1) * 4 + (ul & 1)];
        float blk = __builtin_bit_cast(float, ((unsigned int)hv) << 16);
        float ll = __logf(capv) + capS + __logf(blk);
        __hip_atomic_store(&nll[b], -ll, __ATOMIC_RELEASE,
                           __HIP_MEMORY_SCOPE_AGENT);
        int prev = __hip_atomic_fetch_add(dcnt, 1, __ATOMIC_ACQ_REL,
                                          __HIP_MEMORY_SCOPE_AGENT);
        if (prev == Bb - 1) {           // last finishing batch: write mean
            float s = 0.0f;
            for (int i = 0; i < Bb; ++i)
                s += __hip_atomic_load(&nll[i], __ATOMIC_ACQUIRE,
                                       __HIP_MEMORY_SCOPE_AGENT);
            out[0] = s / (float)Bb;
        }
    }
}

// ---- cooperative fused kernel -------------------------------------------
__global__ __launch_bounds__(512) void fused_kernel(
        const float* __restrict__ logits,
        const int*   __restrict__ targets,
        const int*   __restrict__ logit_lengths,
        const int*   __restrict__ target_lengths,
        unsigned short* __restrict__ gS,
        float* __restrict__ nll,
        int*   __restrict__ dcnt,
        float* __restrict__ out) {
    const int tid  = threadIdx.x;
    const int lane = tid & 63;
    const int wvi  = tid >> 6;

    if (blockIdx.x == gridDim.x - 1 && tid == 0)
        __hip_atomic_store(dcnt, 0, __ATOMIC_RELAXED, __HIP_MEMORY_SCOPE_AGENT);

    // phase 1: lse over all rows, grid-stride by wave
    const int gwaves = gridDim.x * 8;
    for (int wid = blockIdx.x * 8 + wvi; wid < NROWS; wid += gwaves)
        lse_row(wid, lane, logits, targets, gS);

    __threadfence();
    cg::this_grid().sync();

    // phase 2: dp, blocks 0..7, wave 0 only
    if (blockIdx.x >= Bb || wvi != 0) return;
    dp_consume(blockIdx.x, lane, gS, logit_lengths, target_lengths,
               nll, dcnt, out);
}

// ---- fallback two-kernel path -------------------------------------------
__global__ __launch_bounds__(256) void lse_kernel(
        const float* __restrict__ logits,
        const int*   __restrict__ targets,
        unsigned short* __restrict__ gS,
        int* __restrict__ dcnt) {
    if (blockIdx.x == 0 && threadIdx.x == 0)
        __hip_atomic_store(dcnt, 0, __ATOMIC_RELAXED, __HIP_MEMORY_SCOPE_AGENT);
    const int wid  = blockIdx.x * 4 + (threadIdx.x >> 6);
    const int lane = threadIdx.x & 63;
    lse_row(wid, lane, logits, targets, gS);
}

__global__ __launch_bounds__(64) void dp_kernel(
        const unsigned short* __restrict__ gS,
        const int* __restrict__ logit_lengths,
        const int* __restrict__ target_lengths,
        float* __restrict__ nll,
        int*   __restrict__ dcnt,
        float* __restrict__ out) {
    dp_consume(blockIdx.x, threadIdx.x & 63, gS,
               logit_lengths, target_lengths, nll, dcnt, out);
}

extern "C" void kernel_launch(void* const* d_in, const int* in_sizes, int n_in,
                              void* d_out, int out_size, void* d_ws, size_t ws_size,
                              hipStream_t stream) {
    const float* logits         = (const float*)d_in[0];
    const int*   targets        = (const int*)d_in[1];
    const int*   logit_lengths  = (const int*)d_in[2];
    const int*   target_lengths = (const int*)d_in[3];
    float* out = (float*)d_out;

    int* dcnt = (int*)d_ws;                              // 1 int (32B pad)
    unsigned short* gS = (unsigned short*)d_ws + 16;     // 8*244*52*4 bf16
    float* nll = (float*)(gS + (size_t)Bb * DROWS * PAIRS * 4);  // 8 floats

    // occupancy-sized cooperative grid (host-side queries; capture-safe)
    int nb = 0;
    hipOccupancyMaxActiveBlocksPerMultiprocessor(&nb, fused_kernel, 512, 0);
    int dev = 0;
    hipGetDevice(&dev);
    int ncu = 0;
    hipDeviceGetAttribute(&ncu, hipDeviceAttributeMultiprocessorCount, dev);
    int grid = nb * ncu;
    if (grid < Bb) grid = Bb;

    void* args[] = { (void*)&logits, (void*)&targets, (void*)&logit_lengths,
                     (void*)&target_lengths, (void*)&gS, (void*)&nll,
                     (void*)&dcnt, (void*)&out };
    hipError_t err = hipLaunchCooperativeKernel(
        fused_kernel, dim3(grid), dim3(512), args, 0, stream);

    if (err != hipSuccess) {
        // fallback: two-kernel path (r16-equivalent structure)
        lse_kernel<<<NROWS / 4, 256, 0, stream>>>(logits, targets, gS, dcnt);
        dp_kernel<<<Bb, 64, 0, stream>>>(gS, logit_lengths, target_lengths,
                                         nll, dcnt, out);
    }
}

// Round 18
// 150.302 us; speedup vs baseline: 1.5806x; 1.5806x over previous
//
#include <hip/hip_runtime.h>

// RNN-T loss forward: B=8, T=128, U=100, V=1024, BLANK=0.
// INSTRUMENTATION: r16 kernels byte-identical + dp launched 5x total
// (1 real + 4 dummies with private nll/dcnt/out scratch) to pin D_warm.

constexpr int Bb = 8;
constexpr int Tt = 128;
constexpr int Uu = 100;
constexpr int Vv = 1024;
constexpr int UP1 = Uu + 1;
constexpr int DROWS = 244;        // global staging rows per batch
constexpr int PAIRS = 52;         // u-pairs per row
constexpr int ROWB  = PAIRS * 8;  // 416 bytes per row
constexpr int LROWS = 233;        // LDS rows d = 0..232
constexpr int REG   = 29;         // diagonals per copy region
constexpr int NREG  = 8;          // 8 * 29 = 232 diagonals

// ---- bf16 helpers --------------------------------------------------------
__device__ __forceinline__ unsigned short f2bf(float f) {
    unsigned int u = __builtin_bit_cast(unsigned int, f);
    u += 0x7fffu + ((u >> 16) & 1u);
    return (unsigned short)(u >> 16);
}
__device__ __forceinline__ float bflo(unsigned int p) {
    return __builtin_bit_cast(float, p << 16);
}
__device__ __forceinline__ float bfhi(unsigned int p) {
    return __builtin_bit_cast(float, p & 0xffff0000u);
}

// lane l receives lane l-1's value; lane 0 -> 0 (prob identity)
__device__ __forceinline__ float wave_shr1(float x) {
    return __builtin_bit_cast(float, __builtin_amdgcn_update_dpp(
        0, __builtin_bit_cast(int, x), 0x138, 0xf, 0xf, true));
}
__device__ __forceinline__ float readlane_f(float x, int lane) {
    return __builtin_bit_cast(float,
        __builtin_amdgcn_readlane(__builtin_bit_cast(int, x), lane));
}

#define DPP_MAXSTEP(x, ctrl, rmask) {                                        \
    float _t = __builtin_bit_cast(float, __builtin_amdgcn_update_dpp(        \
        __builtin_bit_cast(int, x), __builtin_bit_cast(int, x),              \
        ctrl, rmask, 0xf, false));                                           \
    x = fmaxf(x, _t); }
#define WAVE_SCAN_MAX(x)           \
    DPP_MAXSTEP(x, 0x111, 0xf);    \
    DPP_MAXSTEP(x, 0x112, 0xf);    \
    DPP_MAXSTEP(x, 0x114, 0xf);    \
    DPP_MAXSTEP(x, 0x118, 0xf);    \
    DPP_MAXSTEP(x, 0x142, 0xa);    \
    DPP_MAXSTEP(x, 0x143, 0xc)

// Kernel 1: per (b,t,u) row of V=1024 logits compute lse; stage bf16 PROBS
// interleaved: row d = t+u+1; blank -> [d][u>>1][u&1]; emit -> with s=u+1,
// [d][s>>1][2+(s&1)].  Zeroes the 5 dp done-counter slots.
__global__ __launch_bounds__(256) void lse_kernel(
        const float* __restrict__ logits,
        const int*   __restrict__ targets,
        unsigned short* __restrict__ gS,
        int* __restrict__ dcnt) {
    if (blockIdx.x == 0 && threadIdx.x < 5)
        __hip_atomic_store(&dcnt[threadIdx.x], 0, __ATOMIC_RELAXED,
                           __HIP_MEMORY_SCOPE_AGENT);

    const int wid  = blockIdx.x * 4 + (threadIdx.x >> 6);   // row index
    const int lane = threadIdx.x & 63;
    const int b   = wid / (Tt * UP1);
    const int rem = wid - b * (Tt * UP1);
    const int t   = rem / UP1;
    const int u   = rem - t * UP1;

    const float* row = logits + (size_t)wid * Vv;
    const float4* r4 = (const float4*)row;
    float4 x0 = r4[lane];
    float4 x1 = r4[lane + 64];
    float4 x2 = r4[lane + 128];
    float4 x3 = r4[lane + 192];

    float m = fmaxf(fmaxf(fmaxf(x0.x, x0.y), fmaxf(x0.z, x0.w)),
                    fmaxf(fmaxf(x1.x, x1.y), fmaxf(x1.z, x1.w)));
    m = fmaxf(m, fmaxf(fmaxf(fmaxf(x2.x, x2.y), fmaxf(x2.z, x2.w)),
                       fmaxf(fmaxf(x3.x, x3.y), fmaxf(x3.z, x3.w))));
    #pragma unroll
    for (int d = 32; d > 0; d >>= 1) m = fmaxf(m, __shfl_xor(m, d, 64));

    float s = __expf(x0.x - m) + __expf(x0.y - m) + __expf(x0.z - m) + __expf(x0.w - m)
            + __expf(x1.x - m) + __expf(x1.y - m) + __expf(x1.z - m) + __expf(x1.w - m)
            + __expf(x2.x - m) + __expf(x2.y - m) + __expf(x2.z - m) + __expf(x2.w - m)
            + __expf(x3.x - m) + __expf(x3.y - m) + __expf(x3.z - m) + __expf(x3.w - m);
    #pragma unroll
    for (int d = 32; d > 0; d >>= 1) s += __shfl_xor(s, d, 64);

    float lse = m + __logf(s);

    if (lane == 0) {
        const int dw = t + u + 1;                       // 1..228
        const size_t rowoff = ((size_t)b * DROWS + dw) * (PAIRS * 4);
        gS[rowoff + (u >> 1) * 4 + (u & 1)] = f2bf(__expf(x0.x - lse));
        if (u < Uu) {
            int tgt = targets[b * Uu + u];
            const int sidx = u + 1;
            gS[rowoff + (sidx >> 1) * 4 + 2 + (sidx & 1)] = f2bf(__expf(row[tgt] - lse));
        }
    }
}

// Kernel 2: one 576-thread block (9 waves) per batch element; fused mean.
__global__ __launch_bounds__(576) void dp_kernel(
        const unsigned short* __restrict__ gS,
        const int* __restrict__ logit_lengths,
        const int* __restrict__ target_lengths,
        float* __restrict__ nll,
        int*   __restrict__ dcnt,
        float* __restrict__ out) {
    const int b    = blockIdx.x;
    const int tid  = threadIdx.x;
    const int wvi  = tid >> 6;          // 0 = consumer, 1..8 = copy waves
    const int lane = tid & 63;

    __shared__ __align__(16) unsigned short lBE[LROWS][PAIRS][4];
    __shared__ int sflag[NREG];

    if (tid < NREG) sflag[tid] = 0;
    __syncthreads();

    if (wvi >= 1) {
        // ---- copy wave: region w = rows [1+29w .. 29+29w] -----------------
        const int w = wvi - 1;
        const int row0 = 1 + REG * w;
        const char* gb = (const char*)gS + ((size_t)b * DROWS + row0) * ROWB;
        char* db = (char*)lBE + (size_t)row0 * ROWB;

        uint4 v[12];
        #pragma unroll
        for (int i = 0; i < 12; ++i)
            v[i] = *(const uint4*)(gb + lane * 16 + i * 1024);
        #pragma unroll
        for (int i = 0; i < 11; ++i)
            *(uint4*)(db + lane * 16 + i * 1024) = v[i];
        if (lane < 50)                               // 50*16+11264 < 12064
            *(uint4*)(db + lane * 16 + 11 * 1024) = v[11];

        // zero never-staged pads: E slot s=0; u=101 B/E; pair 51 entirely
        if (lane < REG) {
            const int d = row0 + lane;
            lBE[d][0][2]  = 0;
            lBE[d][50][1] = 0;
            lBE[d][50][3] = 0;
            lBE[d][51][0] = 0; lBE[d][51][1] = 0;
            lBE[d][51][2] = 0; lBE[d][51][3] = 0;
        }
        __hip_atomic_store(&sflag[w], 1, __ATOMIC_RELEASE,
                           __HIP_MEMORY_SCOPE_WORKGROUP);
        return;
    }

    // ---- consumer wave: 232 f32-FMA steps --------------------------------
    const int tl = logit_lengths[b];
    const int ul = target_lengths[b];
    const int t_idx = tl - 2;           // reference reads alpha[tl-2][ul]
    const int dcap  = t_idx + ul;       // diagonal of the readout cell

    const int lpair = (lane < 51) ? lane : 51;   // clamp: lanes>=51 read zeros
    const char* lbase = (const char*)lBE + lpair * 8;

    float P0 = (lane == 0) ? 1.0f : 0.0f;   // exp(alpha) on diag 0
    float P1 = 0.0f;
    float S  = 0.0f;
    float capP0 = (dcap == 0) ? 1.0f : 0.0f, capP1 = 0.0f, capS = 0.0f;

#define PSTEP(dv, w0, w1) do {                                         \
        float Bx = bflo(w0), By = bfhi(w0);                            \
        float Ex = bflo(w1), Ey = bfhi(w1);                            \
        float sh = wave_shr1(P1);                                      \
        float n1 = fmaf(P1, By, P0 * Ey);                              \
        float n0 = fmaf(P0, Bx, sh * Ex);                              \
        P0 = n0; P1 = n1;                                              \
        if ((dv) == dcap) { capP0 = n0; capP1 = n1; capS = S; }        \
    } while (0)

#define RESCALE do {                                                   \
        float gm = fmaxf(P0, P1);                                      \
        WAVE_SCAN_MAX(gm);                                             \
        float mm = fmaxf(readlane_f(gm, 63), 1e-30f);                  \
        float rr = 1.0f / mm;                                          \
        P0 *= rr; P1 *= rr;                                            \
        S += __logf(mm);                                               \
    } while (0)

    // group k covers diagonals 8k+1 .. 8k+8 (k = 0..28)
#define LOADG(UB, UE, k) do {                                          \
        _Pragma("unroll")                                              \
        for (int r = 0; r < 8; ++r) {                                  \
            uint2 q = *(const uint2*)(lbase +                          \
                        (size_t)((k) * 8 + 1 + r) * ROWB);             \
            UB[r] = q.x; UE[r] = q.y;                                  \
        }                                                              \
    } while (0)

#define COMPG(UB, UE, k) do {                                          \
        _Pragma("unroll")                                              \
        for (int r = 0; r < 8; ++r)                                    \
            PSTEP((k) * 8 + 1 + r, UB[r], UE[r]);                      \
        RESCALE;                                                       \
    } while (0)

    int wcur = -1;
#define ENSURE(wn) do {                                                \
        while (wcur < (wn)) {                                          \
            ++wcur;                                                    \
            while (__hip_atomic_load(&sflag[wcur], __ATOMIC_ACQUIRE,   \
                       __HIP_MEMORY_SCOPE_WORKGROUP) == 0)             \
                __builtin_amdgcn_s_sleep(1);                           \
        }                                                              \
    } while (0)

    unsigned int Ab[8], Ae[8], Bb_[8], Be_[8];
    ENSURE(0);
    LOADG(Ab, Ae, 0);
    for (int c = 0; c < 14; ++c) {
        const int k0 = 2 * c, k1 = 2 * c + 1;
        ENSURE((8 * k1 + 7) / REG);
        LOADG(Bb_, Be_, k1);
        COMPG(Ab, Ae, k0);
        if (k1 < 28) {
            ENSURE((8 * (k1 + 1) + 7) / REG);
            LOADG(Ab, Ae, k1 + 1);
        }
        COMPG(Bb_, Be_, k1);
    }
    COMPG(Ab, Ae, 28);                  // group 28 -> diagonal 232
#undef PSTEP
#undef RESCALE
#undef LOADG
#undef COMPG
#undef ENSURE

    // readout: cap value lives on lane ul>>1, slot ul&1
    float w0 = readlane_f(capP0, ul >> 1);
    float w1 = readlane_f(capP1, ul >> 1);
    float capv = (ul & 1) ? w1 : w0;

    if (lane == 0) {
        unsigned short hv = lBE[dcap + 1][ul >> 1][ul & 1];  // blank prob
        float blk = __builtin_bit_cast(float, ((unsigned int)hv) << 16);
        float ll = __logf(capv) + capS + __logf(blk);
        __hip_atomic_store(&nll[b], -ll, __ATOMIC_RELEASE,
                           __HIP_MEMORY_SCOPE_AGENT);
        int prev = __hip_atomic_fetch_add(dcnt, 1, __ATOMIC_ACQ_REL,
                                          __HIP_MEMORY_SCOPE_AGENT);
        if (prev == Bb - 1) {           // last dp block: write the mean
            float s = 0.0f;
            for (int i = 0; i < Bb; ++i)
                s += __hip_atomic_load(&nll[i], __ATOMIC_ACQUIRE,
                                       __HIP_MEMORY_SCOPE_AGENT);
            out[0] = s / (float)Bb;
        }
    }
}

extern "C" void kernel_launch(void* const* d_in, const int* in_sizes, int n_in,
                              void* d_out, int out_size, void* d_ws, size_t ws_size,
                              hipStream_t stream) {
    const float* logits         = (const float*)d_in[0];
    const int*   targets        = (const int*)d_in[1];
    const int*   logit_lengths  = (const int*)d_in[2];
    const int*   target_lengths = (const int*)d_in[3];
    float* out = (float*)d_out;

    int* dcnt = (int*)d_ws;                              // 5 ints (32B pad)
    unsigned short* gS = (unsigned short*)d_ws + 16;     // 8*244*52*4 bf16
    float* nll  = (float*)(gS + (size_t)Bb * DROWS * PAIRS * 4);  // 8 floats
    float* nllX = nll + 8;                               // dummy nll (8)
    float* outX = nll + 16;                              // dummy out (1)

    const int rows = Bb * Tt * UP1;                      // 103424, divisible by 4
    lse_kernel<<<rows / 4, 256, 0, stream>>>(logits, targets, gS, dcnt);
    // dp x5: #1 real; #2-5 timing probes with private scratch
    dp_kernel<<<Bb, 576, 0, stream>>>(gS, logit_lengths, target_lengths,
                                      nll, dcnt + 0, out);
    dp_kernel<<<Bb, 576, 0, stream>>>(gS, logit_lengths, target_lengths,
                                      nllX, dcnt + 1, outX);
    dp_kernel<<<Bb, 576, 0, stream>>>(gS, logit_lengths, target_lengths,
                                      nllX, dcnt + 2, outX);
    dp_kernel<<<Bb, 576, 0, stream>>>(gS, logit_lengths, target_lengths,
                                      nllX, dcnt + 3, outX);
    dp_kernel<<<Bb, 576, 0, stream>>>(gS, logit_lengths, target_lengths,
                                      nllX, dcnt + 4, outX);
}

// Round 19
// 90.070 us; speedup vs baseline: 2.6376x; 1.6687x over previous
//
#include <hip/hip_runtime.h>

// RNN-T loss forward: B=8, T=128, U=100, V=1024, BLANK=0.
// out = mean_b of -( alpha[tl-2, ul] + blank_lp[tl-2, ul] )
//
// lse_kernel (HBM-floor, 424 MB): log-softmax over V; stage the two needed
//   PROBABILITIES (bf16) into diagonal-major interleaved staging
//   gS[b][d][u>>1][B0,B1,E0,E1]. Zeroes dp's done-counter.
// dp_kernel: one block (9 waves) per batch. Waves 1..8: issue-all 12 uint4
//   loads of region w (29 diagonal rows) then bulk-write LDS + zero pads,
//   release LDS flag. Wave 0: diagonals 1..dcap ONLY (stop at the readout
//   diagonal — capture is "P at loop end", no per-step selects) of f32 FMA
//     n1 = fma(P1,B1, P0*E1); n0 = fma(P0,B0, shr1(P1)*E0)
//   in groups of 8 (A/B ping-pong reg sets) + <=7-step tail; exact pow2
//   wave-max rescale per group (integer exponent accumulator S2).
//   Fused mean via 8 device-scope atomics.

constexpr int Bb = 8;
constexpr int Tt = 128;
constexpr int Uu = 100;
constexpr int Vv = 1024;
constexpr int UP1 = Uu + 1;
constexpr int DROWS = 244;        // global staging rows per batch
constexpr int PAIRS = 52;         // u-pairs per row
constexpr int ROWB  = PAIRS * 8;  // 416 bytes per row
constexpr int LROWS = 233;        // LDS rows d = 0..232
constexpr int REG   = 29;         // diagonals per copy region
constexpr int NREG  = 8;          // 8 * 29 = 232 diagonals

// ---- bf16 helpers --------------------------------------------------------
__device__ __forceinline__ unsigned short f2bf(float f) {
    unsigned int u = __builtin_bit_cast(unsigned int, f);
    u += 0x7fffu + ((u >> 16) & 1u);
    return (unsigned short)(u >> 16);
}
__device__ __forceinline__ float bflo(unsigned int p) {
    return __builtin_bit_cast(float, p << 16);
}
__device__ __forceinline__ float bfhi(unsigned int p) {
    return __builtin_bit_cast(float, p & 0xffff0000u);
}

// lane l receives lane l-1's value; lane 0 -> 0 (prob identity)
__device__ __forceinline__ float wave_shr1(float x) {
    return __builtin_bit_cast(float, __builtin_amdgcn_update_dpp(
        0, __builtin_bit_cast(int, x), 0x138, 0xf, 0xf, true));
}
__device__ __forceinline__ float readlane_f(float x, int lane) {
    return __builtin_bit_cast(float,
        __builtin_amdgcn_readlane(__builtin_bit_cast(int, x), lane));
}

#define DPP_MAXSTEP(x, ctrl, rmask) {                                        \
    float _t = __builtin_bit_cast(float, __builtin_amdgcn_update_dpp(        \
        __builtin_bit_cast(int, x), __builtin_bit_cast(int, x),              \
        ctrl, rmask, 0xf, false));                                           \
    x = fmaxf(x, _t); }
#define WAVE_SCAN_MAX(x)           \
    DPP_MAXSTEP(x, 0x111, 0xf);    \
    DPP_MAXSTEP(x, 0x112, 0xf);    \
    DPP_MAXSTEP(x, 0x114, 0xf);    \
    DPP_MAXSTEP(x, 0x118, 0xf);    \
    DPP_MAXSTEP(x, 0x142, 0xa);    \
    DPP_MAXSTEP(x, 0x143, 0xc)

// Kernel 1: per (b,t,u) row of V=1024 logits compute lse; stage bf16 PROBS
// interleaved: row d = t+u+1; blank -> [d][u>>1][u&1]; emit -> with s=u+1,
// [d][s>>1][2+(s&1)].  Zeroes the dp done-counter.
__global__ __launch_bounds__(256) void lse_kernel(
        const float* __restrict__ logits,
        const int*   __restrict__ targets,
        unsigned short* __restrict__ gS,
        int* __restrict__ dcnt) {
    if (blockIdx.x == 0 && threadIdx.x == 0)
        __hip_atomic_store(dcnt, 0, __ATOMIC_RELAXED, __HIP_MEMORY_SCOPE_AGENT);

    const int wid  = blockIdx.x * 4 + (threadIdx.x >> 6);   // row index
    const int lane = threadIdx.x & 63;
    const int b   = wid / (Tt * UP1);
    const int rem = wid - b * (Tt * UP1);
    const int t   = rem / UP1;
    const int u   = rem - t * UP1;

    const float* row = logits + (size_t)wid * Vv;
    const float4* r4 = (const float4*)row;
    float4 x0 = r4[lane];
    float4 x1 = r4[lane + 64];
    float4 x2 = r4[lane + 128];
    float4 x3 = r4[lane + 192];

    float m = fmaxf(fmaxf(fmaxf(x0.x, x0.y), fmaxf(x0.z, x0.w)),
                    fmaxf(fmaxf(x1.x, x1.y), fmaxf(x1.z, x1.w)));
    m = fmaxf(m, fmaxf(fmaxf(fmaxf(x2.x, x2.y), fmaxf(x2.z, x2.w)),
                       fmaxf(fmaxf(x3.x, x3.y), fmaxf(x3.z, x3.w))));
    #pragma unroll
    for (int d = 32; d > 0; d >>= 1) m = fmaxf(m, __shfl_xor(m, d, 64));

    float s = __expf(x0.x - m) + __expf(x0.y - m) + __expf(x0.z - m) + __expf(x0.w - m)
            + __expf(x1.x - m) + __expf(x1.y - m) + __expf(x1.z - m) + __expf(x1.w - m)
            + __expf(x2.x - m) + __expf(x2.y - m) + __expf(x2.z - m) + __expf(x2.w - m)
            + __expf(x3.x - m) + __expf(x3.y - m) + __expf(x3.z - m) + __expf(x3.w - m);
    #pragma unroll
    for (int d = 32; d > 0; d >>= 1) s += __shfl_xor(s, d, 64);

    float lse = m + __logf(s);

    if (lane == 0) {
        const int dw = t + u + 1;                       // 1..228
        const size_t rowoff = ((size_t)b * DROWS + dw) * (PAIRS * 4);
        gS[rowoff + (u >> 1) * 4 + (u & 1)] = f2bf(__expf(x0.x - lse));
        if (u < Uu) {
            int tgt = targets[b * Uu + u];
            const int sidx = u + 1;
            gS[rowoff + (sidx >> 1) * 4 + 2 + (sidx & 1)] = f2bf(__expf(row[tgt] - lse));
        }
    }
}

// Kernel 2: one 576-thread block (9 waves) per batch element; fused mean.
__global__ __launch_bounds__(576) void dp_kernel(
        const unsigned short* __restrict__ gS,
        const int* __restrict__ logit_lengths,
        const int* __restrict__ target_lengths,
        float* __restrict__ nll,
        int*   __restrict__ dcnt,
        float* __restrict__ out) {
    const int b    = blockIdx.x;
    const int tid  = threadIdx.x;
    const int wvi  = tid >> 6;          // 0 = consumer, 1..8 = copy waves
    const int lane = tid & 63;

    __shared__ __align__(16) unsigned short lBE[LROWS][PAIRS][4];
    __shared__ int sflag[NREG];

    if (tid < NREG) sflag[tid] = 0;
    __syncthreads();

    if (wvi >= 1) {
        // ---- copy wave: region w = rows [1+29w .. 29+29w] -----------------
        const int w = wvi - 1;
        const int row0 = 1 + REG * w;
        const char* gb = (const char*)gS + ((size_t)b * DROWS + row0) * ROWB;
        char* db = (char*)lBE + (size_t)row0 * ROWB;

        uint4 v[12];
        #pragma unroll
        for (int i = 0; i < 12; ++i)
            v[i] = *(const uint4*)(gb + lane * 16 + i * 1024);
        #pragma unroll
        for (int i = 0; i < 11; ++i)
            *(uint4*)(db + lane * 16 + i * 1024) = v[i];
        if (lane < 50)                               // 50*16+11264 < 12064
            *(uint4*)(db + lane * 16 + 11 * 1024) = v[11];

        // zero never-staged pads: E slot s=0; u=101 B/E; pair 51 entirely
        if (lane < REG) {
            const int d = row0 + lane;
            lBE[d][0][2]  = 0;
            lBE[d][50][1] = 0;
            lBE[d][50][3] = 0;
            lBE[d][51][0] = 0; lBE[d][51][1] = 0;
            lBE[d][51][2] = 0; lBE[d][51][3] = 0;
        }
        __hip_atomic_store(&sflag[w], 1, __ATOMIC_RELEASE,
                           __HIP_MEMORY_SCOPE_WORKGROUP);
        return;
    }

    // ---- consumer wave: diagonals 1..dcap, f32 FMA -----------------------
    const int tl = logit_lengths[b];
    const int ul = target_lengths[b];
    const int t_idx = tl - 2;           // reference reads alpha[tl-2][ul]
    const int dcap  = t_idx + ul;       // diagonal of the readout cell

    const int lpair = (lane < 51) ? lane : 51;   // clamp: lanes>=51 read zeros
    const char* lbase = (const char*)lBE + lpair * 8;

    float P0 = (lane == 0) ? 1.0f : 0.0f;   // exp(alpha) on diag 0
    float P1 = 0.0f;
    int   S2 = 0;                            // accumulated pow2 scale

#define PSTEP(w0, w1) do {                                             \
        float Bx = bflo(w0), By = bfhi(w0);                            \
        float Ex = bflo(w1), Ey = bfhi(w1);                            \
        float sh = wave_shr1(P1);                                      \
        float n1 = fmaf(P1, By, P0 * Ey);                              \
        float n0 = fmaf(P0, Bx, sh * Ex);                              \
        P0 = n0; P1 = n1;                                              \
    } while (0)

#define RESCALE do {                                                   \
        float gm = fmaxf(P0, P1);                                      \
        WAVE_SCAN_MAX(gm);                                             \
        float mm = fmaxf(readlane_f(gm, 63), 1e-30f);                  \
        unsigned int mb = __builtin_bit_cast(unsigned int, mm);        \
        int E = (int)((mb >> 23) & 0xffu);                             \
        S2 += E - 126;                                                 \
        float rr = __builtin_bit_cast(float, (unsigned int)(253 - E) << 23); \
        P0 *= rr; P1 *= rr;                                            \
    } while (0)

    // group k covers diagonals 8k+1 .. 8k+8
#define LOADG(UB, UE, k) do {                                          \
        _Pragma("unroll")                                              \
        for (int r = 0; r < 8; ++r) {                                  \
            uint2 q = *(const uint2*)(lbase +                          \
                        (size_t)((k) * 8 + 1 + r) * ROWB);             \
            UB[r] = q.x; UE[r] = q.y;                                  \
        }                                                              \
    } while (0)

#define COMPG(UB, UE) do {                                             \
        _Pragma("unroll")                                              \
        for (int r = 0; r < 8; ++r)                                    \
            PSTEP(UB[r], UE[r]);                                       \
        RESCALE;                                                       \
    } while (0)

    int wcur = -1;
#define ENSURE(wn) do {                                                \
        while (wcur < (wn)) {                                          \
            ++wcur;                                                    \
            while (__hip_atomic_load(&sflag[wcur], __ATOMIC_ACQUIRE,   \
                       __HIP_MEMORY_SCOPE_WORKGROUP) == 0)             \
                __builtin_amdgcn_s_sleep(1);                           \
        }                                                              \
    } while (0)

    const int fullg = dcap >> 3;        // full 8-step groups
    const int tail  = dcap & 7;

    unsigned int Ab[8], Ae[8], Bb_[8], Be_[8];
    if (fullg > 0) {
        ENSURE(7 / REG);
        LOADG(Ab, Ae, 0);
    }
    bool useA = true;
    for (int k = 0; k < fullg; ++k) {
        if (k + 1 < fullg) {
            ENSURE((8 * (k + 1) + 7) / REG);
            if (useA) LOADG(Bb_, Be_, k + 1);
            else      LOADG(Ab, Ae, k + 1);
        }
        if (useA) COMPG(Ab, Ae);
        else      COMPG(Bb_, Be_);
        useA = !useA;
    }
    if (tail > 0) {
        ENSURE((dcap - 1) / REG);
        for (int j = 0; j < tail; ++j) {
            const int d = 8 * fullg + 1 + j;
            uint2 q = *(const uint2*)(lbase + (size_t)d * ROWB);
            PSTEP(q.x, q.y);
        }
    }
    ENSURE(dcap / REG);                 // region containing row dcap+1
#undef PSTEP
#undef RESCALE
#undef LOADG
#undef COMPG
#undef ENSURE

    // readout: P after diagonal dcap; value lives on lane ul>>1, slot ul&1
    float w0 = readlane_f(P0, ul >> 1);
    float w1 = readlane_f(P1, ul >> 1);
    float capv = (ul & 1) ? w1 : w0;

    if (lane == 0) {
        unsigned short hv = lBE[dcap + 1][ul >> 1][ul & 1];  // blank prob
        float blk = __builtin_bit_cast(float, ((unsigned int)hv) << 16);
        float ll = __logf(capv) + (float)S2 * 0.6931471805599453f + __logf(blk);
        __hip_atomic_store(&nll[b], -ll, __ATOMIC_RELEASE,
                           __HIP_MEMORY_SCOPE_AGENT);
        int prev = __hip_atomic_fetch_add(dcnt, 1, __ATOMIC_ACQ_REL,
                                          __HIP_MEMORY_SCOPE_AGENT);
        if (prev == Bb - 1) {           // last dp block: write the mean
            float s = 0.0f;
            for (int i = 0; i < Bb; ++i)
                s += __hip_atomic_load(&nll[i], __ATOMIC_ACQUIRE,
                                       __HIP_MEMORY_SCOPE_AGENT);
            out[0] = s / (float)Bb;
        }
    }
}

extern "C" void kernel_launch(void* const* d_in, const int* in_sizes, int n_in,
                              void* d_out, int out_size, void* d_ws, size_t ws_size,
                              hipStream_t stream) {
    const float* logits         = (const float*)d_in[0];
    const int*   targets        = (const int*)d_in[1];
    const int*   logit_lengths  = (const int*)d_in[2];
    const int*   target_lengths = (const int*)d_in[3];
    float* out = (float*)d_out;

    int* dcnt = (int*)d_ws;                              // 1 int (32B pad)
    unsigned short* gS = (unsigned short*)d_ws + 16;     // 8*244*52*4 bf16
    float* nll = (float*)(gS + (size_t)Bb * DROWS * PAIRS * 4);  // 8 floats

    const int rows = Bb * Tt * UP1;                      // 103424, divisible by 4
    lse_kernel<<<rows / 4, 256, 0, stream>>>(logits, targets, gS, dcnt);
    dp_kernel<<<Bb, 576, 0, stream>>>(gS, logit_lengths, target_lengths,
                                      nll, dcnt, out);
}

// Round 20
// 89.080 us; speedup vs baseline: 2.6669x; 1.0111x over previous
//
#include <hip/hip_runtime.h>

// RNN-T loss forward: B=8, T=128, U=100, V=1024, BLANK=0.
// out = mean_b of -( alpha[tl-2, ul] + blank_lp[tl-2, ul] )
//
// lse_kernel (HBM-floor, 424 MB): log-softmax over V; stage the two needed
//   PROBABILITIES (bf16) into diagonal-major interleaved staging
//   gS[b][d][u>>1][B0,B1,E0,E1]. Zeroes dp's done-counter.
// dp_kernel: one block (9 waves) per batch. Waves 1..8: issue-all 12 uint4
//   loads of region w (29 diagonal rows) then bulk-write LDS + zero pads,
//   release LDS flag. Wave 0: 232 diagonals of f32 FMA
//     n1 = fma(P1,B1, P0*E1); n0 = fma(P0,B0, shr1(P1)*E0)
//   (one ds_read_b64 per diagonal), wave-max rescale every 8 diagonals.
//   Fused mean via 8 device-scope atomics.

constexpr int Bb = 8;
constexpr int Tt = 128;
constexpr int Uu = 100;
constexpr int Vv = 1024;
constexpr int UP1 = Uu + 1;
constexpr int DROWS = 244;        // global staging rows per batch
constexpr int PAIRS = 52;         // u-pairs per row
constexpr int ROWB  = PAIRS * 8;  // 416 bytes per row
constexpr int LROWS = 233;        // LDS rows d = 0..232
constexpr int REG   = 29;         // diagonals per copy region
constexpr int NREG  = 8;          // 8 * 29 = 232 diagonals

// ---- bf16 helpers --------------------------------------------------------
__device__ __forceinline__ unsigned short f2bf(float f) {
    unsigned int u = __builtin_bit_cast(unsigned int, f);
    u += 0x7fffu + ((u >> 16) & 1u);
    return (unsigned short)(u >> 16);
}
__device__ __forceinline__ float bflo(unsigned int p) {   // low bf16 -> f32
    return __builtin_bit_cast(float, p << 16);
}
__device__ __forceinline__ float bfhi(unsigned int p) {   // high bf16 -> f32
    return __builtin_bit_cast(float, p & 0xffff0000u);
}

// lane l receives lane l-1's value; lane 0 -> 0 (prob identity)
__device__ __forceinline__ float wave_shr1(float x) {
    return __builtin_bit_cast(float, __builtin_amdgcn_update_dpp(
        0, __builtin_bit_cast(int, x), 0x138, 0xf, 0xf, true));
}
__device__ __forceinline__ float readlane_f(float x, int lane) {
    return __builtin_bit_cast(float,
        __builtin_amdgcn_readlane(__builtin_bit_cast(int, x), lane));
}

// inclusive max-scan over 64 lanes via DPP (lane 63 = global max)
#define DPP_MAXSTEP(x, ctrl, rmask) {                                        \
    float _t = __builtin_bit_cast(float, __builtin_amdgcn_update_dpp(        \
        __builtin_bit_cast(int, x), __builtin_bit_cast(int, x),              \
        ctrl, rmask, 0xf, false));                                           \
    x = fmaxf(x, _t); }
#define WAVE_SCAN_MAX(x)           \
    DPP_MAXSTEP(x, 0x111, 0xf);    \
    DPP_MAXSTEP(x, 0x112, 0xf);    \
    DPP_MAXSTEP(x, 0x114, 0xf);    \
    DPP_MAXSTEP(x, 0x118, 0xf);    \
    DPP_MAXSTEP(x, 0x142, 0xa);    \
    DPP_MAXSTEP(x, 0x143, 0xc)

// Kernel 1: per (b,t,u) row of V=1024 logits compute lse; stage bf16 PROBS
// interleaved: row d = t+u+1; blank -> [d][u>>1][u&1]; emit -> with s=u+1,
// [d][s>>1][2+(s&1)].
__global__ __launch_bounds__(256) void lse_kernel(
        const float* __restrict__ logits,
        const int*   __restrict__ targets,
        unsigned short* __restrict__ gS,
        int* __restrict__ dcnt) {
    if (blockIdx.x == 0 && threadIdx.x == 0)
        __hip_atomic_store(dcnt, 0, __ATOMIC_RELAXED, __HIP_MEMORY_SCOPE_AGENT);

    const int wid  = blockIdx.x * 4 + (threadIdx.x >> 6);   // row index
    const int lane = threadIdx.x & 63;
    const int b   = wid / (Tt * UP1);
    const int rem = wid - b * (Tt * UP1);
    const int t   = rem / UP1;
    const int u   = rem - t * UP1;

    const float* row = logits + (size_t)wid * Vv;
    const float4* r4 = (const float4*)row;
    float4 x0 = r4[lane];
    float4 x1 = r4[lane + 64];
    float4 x2 = r4[lane + 128];
    float4 x3 = r4[lane + 192];

    float m = fmaxf(fmaxf(fmaxf(x0.x, x0.y), fmaxf(x0.z, x0.w)),
                    fmaxf(fmaxf(x1.x, x1.y), fmaxf(x1.z, x1.w)));
    m = fmaxf(m, fmaxf(fmaxf(fmaxf(x2.x, x2.y), fmaxf(x2.z, x2.w)),
                       fmaxf(fmaxf(x3.x, x3.y), fmaxf(x3.z, x3.w))));
    #pragma unroll
    for (int d = 32; d > 0; d >>= 1) m = fmaxf(m, __shfl_xor(m, d, 64));

    float s = __expf(x0.x - m) + __expf(x0.y - m) + __expf(x0.z - m) + __expf(x0.w - m)
            + __expf(x1.x - m) + __expf(x1.y - m) + __expf(x1.z - m) + __expf(x1.w - m)
            + __expf(x2.x - m) + __expf(x2.y - m) + __expf(x2.z - m) + __expf(x2.w - m)
            + __expf(x3.x - m) + __expf(x3.y - m) + __expf(x3.z - m) + __expf(x3.w - m);
    #pragma unroll
    for (int d = 32; d > 0; d >>= 1) s += __shfl_xor(s, d, 64);

    float lse = m + __logf(s);

    if (lane == 0) {
        const int dw = t + u + 1;                       // 1..228
        const size_t rowoff = ((size_t)b * DROWS + dw) * (PAIRS * 4);
        gS[rowoff + (u >> 1) * 4 + (u & 1)] = f2bf(__expf(x0.x - lse));
        if (u < Uu) {
            int tgt = targets[b * Uu + u];
            const int sidx = u + 1;
            gS[rowoff + (sidx >> 1) * 4 + 2 + (sidx & 1)] = f2bf(__expf(row[tgt] - lse));
        }
    }
}

// Kernel 2: one 576-thread block (9 waves) per batch element; fused mean.
__global__ __launch_bounds__(576) void dp_kernel(
        const unsigned short* __restrict__ gS,
        const int* __restrict__ logit_lengths,
        const int* __restrict__ target_lengths,
        float* __restrict__ nll,
        int*   __restrict__ dcnt,
        float* __restrict__ out) {
    const int b    = blockIdx.x;
    const int tid  = threadIdx.x;
    const int wvi  = tid >> 6;          // 0 = consumer, 1..8 = copy waves
    const int lane = tid & 63;

    __shared__ __align__(16) unsigned short lBE[LROWS][PAIRS][4];
    __shared__ int sflag[NREG];

    if (tid < NREG) sflag[tid] = 0;
    __syncthreads();

    if (wvi >= 1) {
        // ---- copy wave: region w = rows [1+29w .. 29+29w] -----------------
        const int w = wvi - 1;
        const int row0 = 1 + REG * w;
        const char* gb = (const char*)gS + ((size_t)b * DROWS + row0) * ROWB;
        char* db = (char*)lBE + (size_t)row0 * ROWB;

        uint4 v[12];
        #pragma unroll
        for (int i = 0; i < 12; ++i)
            v[i] = *(const uint4*)(gb + lane * 16 + i * 1024);
        #pragma unroll
        for (int i = 0; i < 11; ++i)
            *(uint4*)(db + lane * 16 + i * 1024) = v[i];
        if (lane < 50)                               // 50*16+11264 < 12064
            *(uint4*)(db + lane * 16 + 11 * 1024) = v[11];

        // zero never-staged pads: E slot s=0; u=101 B/E; pair 51 entirely
        if (lane < REG) {
            const int d = row0 + lane;
            lBE[d][0][2]  = 0;
            lBE[d][50][1] = 0;
            lBE[d][50][3] = 0;
            lBE[d][51][0] = 0; lBE[d][51][1] = 0;
            lBE[d][51][2] = 0; lBE[d][51][3] = 0;
        }
        __hip_atomic_store(&sflag[w], 1, __ATOMIC_RELEASE,
                           __HIP_MEMORY_SCOPE_WORKGROUP);
        return;
    }

    // ---- consumer wave: 232 f32-FMA steps --------------------------------
    const int tl = logit_lengths[b];
    const int ul = target_lengths[b];
    const int t_idx = tl - 2;           // reference reads alpha[tl-2][ul]
    const int dcap  = t_idx + ul;       // diagonal of the readout cell

    const int lpair = (lane < 51) ? lane : 51;   // clamp: lanes>=51 read zeros
    const char* lbase = (const char*)lBE + lpair * 8;

    float P0 = (lane == 0) ? 1.0f : 0.0f;   // exp(alpha) on diag 0
    float P1 = 0.0f;
    float S  = 0.0f;
    float capP0 = (dcap == 0) ? 1.0f : 0.0f, capP1 = 0.0f, capS = 0.0f;

#define PSTEP(dv, w0, w1) do {                                         \
        float Bx = bflo(w0), By = bfhi(w0);                            \
        float Ex = bflo(w1), Ey = bfhi(w1);                            \
        float sh = wave_shr1(P1);                                      \
        float n1 = fmaf(P1, By, P0 * Ey);                              \
        float n0 = fmaf(P0, Bx, sh * Ex);                              \
        P0 = n0; P1 = n1;                                              \
        if ((dv) == dcap) { capP0 = n0; capP1 = n1; capS = S; }        \
    } while (0)

#define RESCALE do {                                                   \
        float gm = fmaxf(P0, P1);                                      \
        WAVE_SCAN_MAX(gm);                                             \
        float mm = fmaxf(readlane_f(gm, 63), 1e-30f);                  \
        float rr = 1.0f / mm;                                          \
        P0 *= rr; P1 *= rr;                                            \
        S += __logf(mm);                                               \
    } while (0)

    // group k covers diagonals 8k+1 .. 8k+8 (k = 0..28)
#define LOADG(UB, UE, k) do {                                          \
        _Pragma("unroll")                                              \
        for (int r = 0; r < 8; ++r) {                                  \
            uint2 q = *(const uint2*)(lbase +                          \
                        (size_t)((k) * 8 + 1 + r) * ROWB);             \
            UB[r] = q.x; UE[r] = q.y;                                  \
        }                                                              \
    } while (0)

#define COMPG(UB, UE, k) do {                                          \
        _Pragma("unroll")                                              \
        for (int r = 0; r < 8; ++r)                                    \
            PSTEP((k) * 8 + 1 + r, UB[r], UE[r]);                      \
        RESCALE;                                                       \
    } while (0)

    int wcur = -1;
#define ENSURE(wn) do {                                                \
        while (wcur < (wn)) {                                          \
            ++wcur;                                                    \
            while (__hip_atomic_load(&sflag[wcur], __ATOMIC_ACQUIRE,   \
                       __HIP_MEMORY_SCOPE_WORKGROUP) == 0)             \
                __builtin_amdgcn_s_sleep(1);                           \
        }                                                              \
    } while (0)

    unsigned int Ab[8], Ae[8], Bb_[8], Be_[8];
    ENSURE(0);
    LOADG(Ab, Ae, 0);
    for (int c = 0; c < 14; ++c) {
        const int k0 = 2 * c, k1 = 2 * c + 1;
        ENSURE((8 * k1 + 7) / REG);
        LOADG(Bb_, Be_, k1);
        COMPG(Ab, Ae, k0);
        if (k1 < 28) {
            ENSURE((8 * (k1 + 1) + 7) / REG);
            LOADG(Ab, Ae, k1 + 1);
        }
        COMPG(Bb_, Be_, k1);
    }
    COMPG(Ab, Ae, 28);                  // group 28 -> diagonal 232
#undef PSTEP
#undef RESCALE
#undef LOADG
#undef COMPG
#undef ENSURE

    // readout: cap value lives on lane ul>>1, slot ul&1
    float w0 = readlane_f(capP0, ul >> 1);
    float w1 = readlane_f(capP1, ul >> 1);
    float capv = (ul & 1) ? w1 : w0;

    if (lane == 0) {
        unsigned short hv = lBE[dcap + 1][ul >> 1][ul & 1];  // blank prob
        float blk = __builtin_bit_cast(float, ((unsigned int)hv) << 16);
        float ll = __logf(capv) + capS + __logf(blk);
        __hip_atomic_store(&nll[b], -ll, __ATOMIC_RELEASE,
                           __HIP_MEMORY_SCOPE_AGENT);
        int prev = __hip_atomic_fetch_add(dcnt, 1, __ATOMIC_ACQ_REL,
                                          __HIP_MEMORY_SCOPE_AGENT);
        if (prev == Bb - 1) {           // last dp block: write the mean
            float s = 0.0f;
            for (int i = 0; i < Bb; ++i)
                s += __hip_atomic_load(&nll[i], __ATOMIC_ACQUIRE,
                                       __HIP_MEMORY_SCOPE_AGENT);
            out[0] = s / (float)Bb;
        }
    }
}

extern "C" void kernel_launch(void* const* d_in, const int* in_sizes, int n_in,
                              void* d_out, int out_size, void* d_ws, size_t ws_size,
                              hipStream_t stream) {
    const float* logits         = (const float*)d_in[0];
    const int*   targets        = (const int*)d_in[1];
    const int*   logit_lengths  = (const int*)d_in[2];
    const int*   target_lengths = (const int*)d_in[3];
    float* out = (float*)d_out;

    int* dcnt = (int*)d_ws;                              // 1 int (16B pad)
    unsigned short* gS = (unsigned short*)d_ws + 16;     // 8*244*52*4 bf16
    float* nll = (float*)(gS + (size_t)Bb * DROWS * PAIRS * 4);  // 8 floats

    const int rows = Bb * Tt * UP1;                      // 103424, divisible by 4
    lse_kernel<<<rows / 4, 256, 0, stream>>>(logits, targets, gS, dcnt);
    dp_kernel<<<Bb, 576, 0, stream>>>(gS, logit_lengths, target_lengths,
                                      nll, dcnt, out);
}